// Round 10
// baseline (63.230 us; speedup 1.0000x reference)
//
#include <hip/hip_runtime.h>
#include <hip/hip_bf16.h>

#define BATCH 8
#define NC    64      // channels (Cin == Cout == 64)
#define HH    32
#define WW    64
#define NN    2048    // HH*WW
#define NCP   72      // padded ci slots per LDS row (conv)
#define NCHUNK 4      // attention j-split factor
#define KVBLK 64      // attention j-tile width

typedef __attribute__((ext_vector_type(8))) short bf16x8;
typedef __attribute__((ext_vector_type(4))) short short4v;
typedef __attribute__((ext_vector_type(4))) float f32x4;

__device__ __forceinline__ unsigned short f2bf(float f) {
    union { float f; unsigned u; } v; v.f = f;
    unsigned r = v.u + 0x7fffu + ((v.u >> 16) & 1u);   // RNE
    return (unsigned short)(r >> 16);
}
__device__ __forceinline__ float bf2f(unsigned short h) {
    union { unsigned u; float f; } v; v.u = ((unsigned)h) << 16;
    return v.f;
}

__device__ __forceinline__ bf16x8 load8(const unsigned short* a, const unsigned short* b) {
    short4v lo = *(const short4v*)a;
    short4v hi = *(const short4v*)b;
    return __builtin_shufflevector(lo, hi, 0, 1, 2, 3, 4, 5, 6, 7);
}

// slot j (0..63) -> original ci (conv K-permutation; same map on both operands)
__device__ __forceinline__ int ci_of_slot(int j) {
    return (j & 32) | (((j >> 2) & 1) << 4) | (((j >> 3) & 3) << 2) | (j & 3);
}

// ---------------------------------------------------------------------------
// prep_wx: fused weight+input prep (one launch). UNCHANGED from round 9.
//  blocks [0,432):  wb bf16 [tap][row=conv*64+cout][slot]
//  blocks [432,944): xb bf16 [b][y][xx][slot], per (b, y, x-half)
// ---------------------------------------------------------------------------
__global__ __launch_bounds__(256) void prep_wx(
    const float* __restrict__ wq, const float* __restrict__ wk,
    const float* __restrict__ wv, const float* __restrict__ x,
    unsigned short* __restrict__ wb, unsigned short* __restrict__ xb)
{
    __shared__ unsigned short T[32][72];   // [xx][ci] (prep_x part only)
    const int bid = blockIdx.x;
    const int tid = threadIdx.x;

    if (bid < 432) {
        const int idx = bid * 256 + tid;
        if (idx >= 9 * 192 * 64) return;
        const int j    = idx & 63;
        const int row  = (idx >> 6) % 192;
        const int tap  = idx / (192 * 64);
        const int ci   = ci_of_slot(j);
        const int conv = row >> 6;
        const int cout = row & 63;
        const float* ww = (conv == 0) ? wq : (conv == 1) ? wk : wv;
        wb[idx] = f2bf(ww[((size_t)cout * 64 + ci) * 9 + tap]);
        return;
    }

    const int bid2 = bid - 432;            // 0..511
    const int bi   = bid2 >> 6;
    const int rem  = bid2 & 63;
    const int y    = rem >> 1;
    const int x0   = (rem & 1) * 32;

#pragma unroll
    for (int pass = 0; pass < 8; ++pass) {
        const int idx = pass * 256 + tid;          // 2048 elements
        const int ci = idx >> 5, xx0 = idx & 31;
        T[xx0][ci] = f2bf(x[(((size_t)bi * 64 + ci) * 32 + y) * 64 + x0 + xx0]);
    }
    __syncthreads();

    {
        const int xx0 = tid >> 3, j8 = tid & 7;    // 256 uint4 chunks
        unsigned short h[8];
#pragma unroll
        for (int e = 0; e < 8; ++e)
            h[e] = T[xx0][ci_of_slot(j8 * 8 + e)];
        uint4 u;
        u.x = (unsigned)h[0] | ((unsigned)h[1] << 16);
        u.y = (unsigned)h[2] | ((unsigned)h[3] << 16);
        u.z = (unsigned)h[4] | ((unsigned)h[5] << 16);
        u.w = (unsigned)h[6] | ((unsigned)h[7] << 16);
        *(uint4*)(xb + ((((size_t)bi * 32 + y) * 64 + x0 + xx0) * 64) + j8 * 8) = u;
    }
}

// ---------------------------------------------------------------------------
// conv_mfma: implicit-GEMM conv, restructured: block = (b, y, mh) where mh
// selects 16 M-rows of the fused 192-row space. ALL 9 taps of W (20.7 KB) and
// the full-width X tile (28.5 KB) staged in LDS ONCE -> 49 KB, 3 blocks/CU,
// ZERO barriers and ZERO global loads in the 9-tap loop. Grid 3072.
// Wave = 16 M-rows x 16 px (pp = wave id). Per tap: 4 ds_read_b128 + 2 MFMA.
// ---------------------------------------------------------------------------
__global__ __launch_bounds__(256) void conv_mfma(
    const unsigned short* __restrict__ xb,   // [b][y][xx][slot]
    const unsigned short* __restrict__ wb,   // [tap][row][slot]
    const float* __restrict__ bq, const float* __restrict__ bk,
    const float* __restrict__ bv,
    unsigned short* __restrict__ qT,         // [b][n][c]
    unsigned short* __restrict__ kT,         // [b][n][c]
    unsigned short* __restrict__ vv)         // [b][c][n]
{
    __shared__ __align__(16) unsigned short Xs[3][66][NCP];   // 28.5 KB
    __shared__ __align__(16) unsigned short Ws[9][16][NCP];   // 20.3 KB

    const int bid = blockIdx.x;      // 3072 = (bi*32 + y)*12 + mh
    const int mh  = bid % 12;        // 16-row M-slab
    const int t2  = bid / 12;
    const int y   = t2 & 31;
    const int bi  = t2 >> 5;
    const int tid = threadIdx.x;
    const int l   = tid & 63;
    const int w   = tid >> 6;        // = pp (16-px slab)
    const int g   = l >> 4;
    const int li  = l & 15;

    // ---- stage X tile: rows y-1..y+1, cols -1..64 (zero halo) ----
#pragma unroll
    for (int r = 0; r < 3; ++r) {
        const int yy = y + r - 1;
#pragma unroll
        for (int pass = 0; pass < 3; ++pass) {
            const int chunk = pass * 256 + tid;          // 528 chunks
            if (chunk >= 528) break;
            const int c = chunk >> 3, ci8 = chunk & 7;   // c: 0..65
            uint4 d = {0, 0, 0, 0};
            const int xx = c - 1;
            if (yy >= 0 && yy < HH && xx >= 0 && xx < WW)
                d = *(const uint4*)(xb + ((((size_t)bi * HH + yy) * WW + xx) * 64) + ci8 * 8);
            *(uint4*)&Xs[r][c][ci8 * 8] = d;
        }
    }
    // ---- stage ALL 9 taps of this slab's W (16 rows each) ----
#pragma unroll
    for (int pass = 0; pass < 5; ++pass) {
        const int chunk = pass * 256 + tid;              // 1152 chunks
        if (chunk >= 1152) break;
        const int tap = chunk >> 7;                      // /128
        const int rr  = (chunk >> 3) & 15;
        const int ci8 = chunk & 7;
        uint4 d = *(const uint4*)(wb + ((size_t)(tap * 192 + mh * 16 + rr)) * 64 + ci8 * 8);
        *(uint4*)&Ws[tap][rr][ci8 * 8] = d;
    }
    __syncthreads();

    f32x4 acc = {0, 0, 0, 0};

#pragma unroll
    for (int tap = 0; tap < 9; ++tap) {
        const int ky = tap / 3, kx = tap % 3;
        const bf16x8 wf0 = *(const bf16x8*)&Ws[tap][li][g * 8];
        const bf16x8 wf1 = *(const bf16x8*)&Ws[tap][li][32 + g * 8];
        const int c = w * 16 + li + kx;                  // 0..65
        const bf16x8 xf0 = *(const bf16x8*)&Xs[ky][c][g * 8];
        const bf16x8 xf1 = *(const bf16x8*)&Xs[ky][c][32 + g * 8];
        acc = __builtin_amdgcn_mfma_f32_16x16x32_bf16(wf0, xf0, acc, 0, 0, 0);
        acc = __builtin_amdgcn_mfma_f32_16x16x32_bf16(wf1, xf1, acc, 0, 0, 0);
    }

    // ---- epilogue: bias + store. D: cout = mh*16 + 4g + r, pixel n = li ----
    const int n     = y * 64 + w * 16 + li;
    const int conv  = mh >> 2;
    const int cout0 = (mh & 3) * 16 + 4 * g;
    const float* bias = (conv == 0) ? bq : (conv == 1) ? bk : bv;
    float v0 = acc[0] + bias[cout0 + 0];
    float v1 = acc[1] + bias[cout0 + 1];
    float v2 = acc[2] + bias[cout0 + 2];
    float v3 = acc[3] + bias[cout0 + 3];
    if (conv < 2) {
        uint2 pk;
        pk.x = (unsigned)f2bf(v0) | ((unsigned)f2bf(v1) << 16);
        pk.y = (unsigned)f2bf(v2) | ((unsigned)f2bf(v3) << 16);
        unsigned short* dst = ((conv == 0) ? qT : kT) +
                              ((size_t)bi * NN + n) * NC + cout0;
        *(uint2*)dst = pk;
    } else {
        vv[((size_t)bi * NC + cout0 + 0) * NN + n] = f2bf(v0);
        vv[((size_t)bi * NC + cout0 + 1) * NN + n] = f2bf(v1);
        vv[((size_t)bi * NC + cout0 + 2) * NN + n] = f2bf(v2);
        vv[((size_t)bi * NC + cout0 + 3) * NN + n] = f2bf(v3);
    }
}

// ---------------------------------------------------------------------------
// attn_mfma_split: flash attention over one j-chunk (NN/NCHUNK = 512 cols),
// KVBLK = 64 -> 8 iterations. UNCHANGED from rounds 8/9.
// ---------------------------------------------------------------------------
__global__ __launch_bounds__(256) void attn_mfma_split(
    const unsigned short* __restrict__ qT,  // [b][n][c]
    const unsigned short* __restrict__ kT,  // [b][n][c]
    const unsigned short* __restrict__ vv,  // [b][c][n]
    unsigned short* __restrict__ Po,        // [chunk][b][i][slot] bf16
    float* __restrict__ Pm, float* __restrict__ Pl)  // [chunk][b][i]
{
    __shared__ __align__(16) unsigned short Ks[2][KVBLK][72];  // 18.4 KB
    __shared__ __align__(16) unsigned short Vs[2][64][72];     // 18.4 KB

    const int bid  = blockIdx.x;
    const int g8   = bid & 7;
    const int s    = bid >> 3;          // 0..127
    const int qq   = s >> 5;            // 0..3
    const int it   = s & 31;            // i-tile
    const int G    = g8 + 8 * qq;       // 0..31 = 4*bi + chunk
    const int bi   = G >> 2;
    const int chunk= G & 3;

    const int tid = threadIdx.x;
    const int l   = tid & 63;
    const int w   = tid >> 6;
    const int g   = l >> 4;
    const int li  = l & 15;
    const int i0  = it * 64;
    const int jbase = chunk * (NN / NCHUNK);
    const int NT  = (NN / NCHUNK) / KVBLK;    // 8 j-tiles

    const unsigned short* qb = qT + (size_t)bi * NN * NC;
    const unsigned short* kb = kT + (size_t)bi * NN * NC;
    const unsigned short* vb = vv + (size_t)bi * NC * NN;

    // ---- Q fragments straight from global (one-time) ----
    const int qrow = i0 + w * 16 + li;
    const bf16x8 qf0 = load8(qb + (size_t)qrow * NC + 4 * g,      qb + (size_t)qrow * NC + 16 + 4 * g);
    const bf16x8 qf1 = load8(qb + (size_t)qrow * NC + 32 + 4 * g, qb + (size_t)qrow * NC + 48 + 4 * g);

    // ---- prologue: stage j-tile 0 (K: 64 rows x 64ch, V: 64ch x 64 j) ----
    uint4 kd[2], vd[2];
#pragma unroll
    for (int u = 0; u < 2; ++u) {
        const int chunkid = u * 256 + tid;          // 512 chunks each
        const int r = chunkid >> 3, c8 = chunkid & 7;
        kd[u] = *(const uint4*)(kb + ((size_t)(jbase + r)) * NC + c8 * 8);
        vd[u] = *(const uint4*)(vb + (size_t)r * NN + jbase + c8 * 8);
        *(uint4*)&Ks[0][r][c8 * 8] = kd[u];
        *(uint4*)&Vs[0][r][c8 * 8] = vd[u];
    }
    __syncthreads();

    f32x4 o0 = {0,0,0,0}, o1 = {0,0,0,0}, o2 = {0,0,0,0}, o3 = {0,0,0,0};
    float m = -1e30f, lsum = 0.0f;

    for (int t = 0; t < NT; ++t) {
        const int cur = t & 1;
        if (t < NT - 1) {
            const int j0 = jbase + (t + 1) * KVBLK;
#pragma unroll
            for (int u = 0; u < 2; ++u) {
                const int chunkid = u * 256 + tid;
                const int r = chunkid >> 3, c8 = chunkid & 7;
                kd[u] = *(const uint4*)(kb + ((size_t)(j0 + r)) * NC + c8 * 8);
                vd[u] = *(const uint4*)(vb + (size_t)r * NN + j0 + c8 * 8);
            }
        }

        // ---- QK^T: 4 j-subtiles of 16 rows ----
        f32x4 d[4];
        __builtin_amdgcn_s_setprio(1);
#pragma unroll
        for (int jb = 0; jb < 4; ++jb) {
            const bf16x8 kfa = load8(&Ks[cur][jb * 16 + li][4 * g],      &Ks[cur][jb * 16 + li][16 + 4 * g]);
            const bf16x8 kfb = load8(&Ks[cur][jb * 16 + li][32 + 4 * g], &Ks[cur][jb * 16 + li][48 + 4 * g]);
            const f32x4 z = {0,0,0,0};
            d[jb] = __builtin_amdgcn_mfma_f32_16x16x32_bf16(kfa, qf0, z, 0, 0, 0);
            d[jb] = __builtin_amdgcn_mfma_f32_16x16x32_bf16(kfb, qf1, d[jb], 0, 0, 0);
        }
        __builtin_amdgcn_s_setprio(0);

        // ---- online softmax over 16 lane-local scores (row i = li) ----
        float p[16];
#pragma unroll
        for (int jb = 0; jb < 4; ++jb)
#pragma unroll
            for (int e = 0; e < 4; ++e) p[jb * 4 + e] = d[jb][e];

        float pmax = p[0];
#pragma unroll
        for (int e = 1; e < 16; ++e) pmax = fmaxf(pmax, p[e]);
        pmax = fmaxf(pmax, __shfl_xor(pmax, 16));
        pmax = fmaxf(pmax, __shfl_xor(pmax, 32));

        if (!__all(pmax <= m)) {
            const float mn = fmaxf(m, pmax);
            const float alpha = __expf(m - mn);   // ==1 for rows whose max held
            m = mn;
#pragma unroll
            for (int r = 0; r < 4; ++r) {
                const float ar = __shfl(alpha, 4 * g + r, 16);
                o0[r] *= ar; o1[r] *= ar; o2[r] *= ar; o3[r] *= ar;
            }
            lsum *= alpha;
        }

        float ls = 0.0f;
#pragma unroll
        for (int e = 0; e < 16; ++e) {
            p[e] = __expf(p[e] - m);
            ls += p[e];
        }
        ls += __shfl_xor(ls, 16);
        ls += __shfl_xor(ls, 32);
        lsum += ls;

        bf16x8 pf0, pf1;
#pragma unroll
        for (int e = 0; e < 8; ++e) {
            pf0[e] = (short)f2bf(p[e]);
            pf1[e] = (short)f2bf(p[8 + e]);
        }

        // ---- PV: o[cb] += pf0*V[cb][j0-31] + pf1*V[cb][j32-63] ----
        __builtin_amdgcn_s_setprio(1);
        {
            const bf16x8 va0 = load8(&Vs[cur][li][4 * g],      &Vs[cur][li][16 + 4 * g]);
            const bf16x8 va1 = load8(&Vs[cur][li][32 + 4 * g], &Vs[cur][li][48 + 4 * g]);
            o0 = __builtin_amdgcn_mfma_f32_16x16x32_bf16(pf0, va0, o0, 0, 0, 0);
            o0 = __builtin_amdgcn_mfma_f32_16x16x32_bf16(pf1, va1, o0, 0, 0, 0);
            const bf16x8 vb0 = load8(&Vs[cur][16 + li][4 * g],      &Vs[cur][16 + li][16 + 4 * g]);
            const bf16x8 vb1 = load8(&Vs[cur][16 + li][32 + 4 * g], &Vs[cur][16 + li][48 + 4 * g]);
            o1 = __builtin_amdgcn_mfma_f32_16x16x32_bf16(pf0, vb0, o1, 0, 0, 0);
            o1 = __builtin_amdgcn_mfma_f32_16x16x32_bf16(pf1, vb1, o1, 0, 0, 0);
            const bf16x8 vc0 = load8(&Vs[cur][32 + li][4 * g],      &Vs[cur][32 + li][16 + 4 * g]);
            const bf16x8 vc1 = load8(&Vs[cur][32 + li][32 + 4 * g], &Vs[cur][32 + li][48 + 4 * g]);
            o2 = __builtin_amdgcn_mfma_f32_16x16x32_bf16(pf0, vc0, o2, 0, 0, 0);
            o2 = __builtin_amdgcn_mfma_f32_16x16x32_bf16(pf1, vc1, o2, 0, 0, 0);
            const bf16x8 vd0 = load8(&Vs[cur][48 + li][4 * g],      &Vs[cur][48 + li][16 + 4 * g]);
            const bf16x8 vd1 = load8(&Vs[cur][48 + li][32 + 4 * g], &Vs[cur][48 + li][48 + 4 * g]);
            o3 = __builtin_amdgcn_mfma_f32_16x16x32_bf16(pf0, vd0, o3, 0, 0, 0);
            o3 = __builtin_amdgcn_mfma_f32_16x16x32_bf16(pf1, vd1, o3, 0, 0, 0);
        }
        __builtin_amdgcn_s_setprio(0);

        if (t < NT - 1) {
#pragma unroll
            for (int u = 0; u < 2; ++u) {
                const int chunkid = u * 256 + tid;
                const int r = chunkid >> 3, c8 = chunkid & 7;
                *(uint4*)&Ks[cur ^ 1][r][c8 * 8] = kd[u];
                *(uint4*)&Vs[cur ^ 1][r][c8 * 8] = vd[u];
            }
        }
        __syncthreads();
    }

    // ---- store partials, PACKED: row i, slots 4*li..4*li+3 = channels
    //      {li, 16+li, 32+li, 48+li}; combine un-permutes: c = (s&3)*16+(s>>2)
    unsigned short* pob = Po + (((size_t)chunk * BATCH + bi) * NN) * NC;
#pragma unroll
    for (int r = 0; r < 4; ++r) {
        const int row = i0 + w * 16 + 4 * g + r;
        uint2 pk;
        pk.x = (unsigned)f2bf(o0[r]) | ((unsigned)f2bf(o1[r]) << 16);
        pk.y = (unsigned)f2bf(o2[r]) | ((unsigned)f2bf(o3[r]) << 16);
        *(uint2*)(pob + (size_t)row * NC + 4 * li) = pk;
    }
    if (g == 0) {
        const size_t mi = ((size_t)chunk * BATCH + bi) * NN + i0 + w * 16 + li;
        Pm[mi] = m;
        Pl[mi] = lsum;
    }
}

// ---------------------------------------------------------------------------
// attn_combine: merge NCHUNK partials exactly. UNCHANGED from round 9.
// ---------------------------------------------------------------------------
__global__ __launch_bounds__(256) void attn_combine(
    const unsigned short* __restrict__ Po,
    const float* __restrict__ Pm, const float* __restrict__ Pl,
    float* __restrict__ out)
{
    __shared__ float wf[NCHUNK][16];
    __shared__ float Os[16][66];

    const int bi = blockIdx.x >> 7;
    const int it = blockIdx.x & 127;
    const int i0 = it * 16;
    const int tid = threadIdx.x;

    if (tid < 64) {
        const int ch = tid >> 4, il = tid & 15;
        wf[ch][il] = Pm[((size_t)ch * BATCH + bi) * NN + i0 + il];
    }
    __syncthreads();
    if (tid < 16) {
        float mv[NCHUNK];
        float ms = -1e30f;
#pragma unroll
        for (int ch = 0; ch < NCHUNK; ++ch) {
            mv[ch] = wf[ch][tid];
            ms = fmaxf(ms, mv[ch]);
        }
        float denom = 0.0f;
        float ev[NCHUNK];
#pragma unroll
        for (int ch = 0; ch < NCHUNK; ++ch) {
            ev[ch] = __expf(mv[ch] - ms);
            denom = fmaf(ev[ch], Pl[((size_t)ch * BATCH + bi) * NN + i0 + tid], denom);
        }
        const float inv = 1.0f / denom;
#pragma unroll
        for (int ch = 0; ch < NCHUNK; ++ch)
            wf[ch][tid] = ev[ch] * inv;
    }
    __syncthreads();

    {
        const int rg = tid >> 6, ss = tid & 63;    // 4 row-groups of 4
        const int c = (ss & 3) * 16 + (ss >> 2);
#pragma unroll
        for (int k = 0; k < 4; ++k) {
            const int i = rg * 4 + k;
            float acc = 0.0f;
#pragma unroll
            for (int ch = 0; ch < NCHUNK; ++ch) {
                const float pv = bf2f(Po[(((size_t)ch * BATCH + bi) * NN + i0 + i) * NC + ss]);
                acc = fmaf(wf[ch][i], pv, acc);
            }
            Os[i][c] = acc;
        }
    }
    __syncthreads();

    {
        const int c = tid & 63, rg = tid >> 6;
        float* ob = out + ((size_t)bi * NC + c) * NN + i0 + rg * 4;
        *(float4*)ob = make_float4(Os[rg * 4 + 0][c], Os[rg * 4 + 1][c],
                                   Os[rg * 4 + 2][c], Os[rg * 4 + 3][c]);
    }
}

// ---------------------------------------------------------------------------
extern "C" void kernel_launch(void* const* d_in, const int* in_sizes, int n_in,
                              void* d_out, int out_size, void* d_ws, size_t ws_size,
                              hipStream_t stream)
{
    const float* x  = (const float*)d_in[0];
    const float* wq = (const float*)d_in[1];
    const float* bq = (const float*)d_in[2];
    const float* wk = (const float*)d_in[3];
    const float* bk = (const float*)d_in[4];
    const float* wv = (const float*)d_in[5];
    const float* bv = (const float*)d_in[6];

    unsigned short* ws16 = (unsigned short*)d_ws;
    const size_t TEN = (size_t)BATCH * NN * NC;                 // 1M elems
    unsigned short* qT = ws16;                                  // 2MB
    unsigned short* kT = ws16 + TEN;                            // 2MB
    unsigned short* vv = ws16 + 2 * TEN;                        // 2MB
    unsigned short* xb = ws16 + 3 * TEN;                        // 2MB
    unsigned short* wb = ws16 + 4 * TEN;                        // 216KB (pad to 128K elems)
    unsigned short* Po = ws16 + 4 * TEN + 131072;               // NCHUNK*TEN bf16 = 8MB
    float* Pm = (float*)(ws16 + 4 * TEN + 131072 + (size_t)NCHUNK * TEN); // 256KB
    float* Pl = Pm + (size_t)NCHUNK * BATCH * NN;                          // 256KB
    float* out = (float*)d_out;

    prep_wx<<<dim3(944), 256, 0, stream>>>(wq, wk, wv, x, wb, xb);
    conv_mfma<<<dim3(3072), 256, 0, stream>>>(xb, wb, bq, bk, bv, qT, kT, vv);
    attn_mfma_split<<<dim3(BATCH * 32 * NCHUNK), 256, 0, stream>>>(qT, kT, vv, Po, Pm, Pl);
    attn_combine<<<dim3(BATCH * 128), 256, 0, stream>>>(Po, Pm, Pl, out);
}